// Round 4
// baseline (118.824 us; speedup 1.0000x reference)
//
#include <hip/hip_runtime.h>
#include <math.h>

// ---- problem constants (fixed by reference) ----
#define T_TOK 1024
#define H_DIM 768
#define I_DIM 3072
#define E_NUM 8
#define BM    128
#define BK    64
#define MSLOTS 16   // max m-tiles: sum ceil(c_e/128) <= 8 + 7 = 15
#define KSPLIT2 4   // FFN2 split-K factor

typedef __attribute__((ext_vector_type(8))) short  short8;   // 8 bf16 (4 VGPRs)
typedef __attribute__((ext_vector_type(4))) float  f32x4;

__device__ __forceinline__ unsigned short f2bf(float f) {
  union { float f; unsigned u; } a; a.f = f;
  unsigned r = a.u + 0x7FFFu + ((a.u >> 16) & 1u);  // RTNE
  return (unsigned short)(r >> 16);
}
__device__ __forceinline__ float gelu_exact(float x) {
  return 0.5f * x * (1.0f + erff(x * 0.70710678118654752f));
}

// ---- kernel 1: deterministic expert routing (ballot rank) + tile list ----
__global__ __launch_bounds__(1024) void route_kernel(
    const int* __restrict__ eidx, int* __restrict__ perm,
    int* __restrict__ tile_e, int* __restrict__ tile_row,
    int* __restrict__ tile_len, int* __restrict__ ntiles) {
  __shared__ int wcnt[16][E_NUM];   // per-wave per-expert count
  __shared__ int wpre[16][E_NUM];   // exclusive prefix over waves
  __shared__ int offsh[E_NUM + 1];
  const int t = threadIdx.x;        // 1024
  const int lane = t & 63, wave = t >> 6;
  const int e = eidx[t];
  unsigned long long myMask = 0;
#pragma unroll
  for (int ee = 0; ee < E_NUM; ++ee) {
    unsigned long long m = __ballot(e == ee);
    if (ee == e) myMask = m;
    if (lane == 0) wcnt[wave][ee] = __popcll(m);
  }
  const int rank = __popcll(myMask & ((1ull << lane) - 1ull));
  __syncthreads();
  if (t < 16 * E_NUM) {             // pair (w, e)
    const int w = t >> 3, ee = t & 7;
    int p = 0;
    for (int w2 = 0; w2 < w; ++w2) p += wcnt[w2][ee];
    wpre[w][ee] = p;
  }
  __syncthreads();
  if (t <= E_NUM) {
    int off = 0;
    for (int ee = 0; ee < t; ++ee) off += wpre[15][ee] + wcnt[15][ee];
    offsh[t] = off;
  }
  __syncthreads();
  perm[offsh[e] + wpre[wave][e] + rank] = t;
  if (t == 0) {
    int n = 0;
    for (int ee = 0; ee < E_NUM; ++ee)
      for (int r = offsh[ee]; r < offsh[ee + 1]; r += BM) {
        tile_e[n] = ee; tile_row[n] = r;
        tile_len[n] = min(offsh[ee + 1] - r, BM); ++n;
      }
    *ntiles = n;
    for (int i = n; i < MSLOTS; ++i) { tile_e[i] = 0; tile_row[i] = 0; tile_len[i] = 0; }
  }
}

// ---- kernel 2: gather x into perm order, f32 -> bf16 ----
__global__ void gather_kernel(const float* __restrict__ x,
                              const int* __restrict__ perm,
                              unsigned short* __restrict__ xg) {
  const int idx = blockIdx.x * 256 + threadIdx.x;
  if (idx >= T_TOK * (H_DIM / 8)) return;
  const int p = idx / (H_DIM / 8);
  const int c = (idx % (H_DIM / 8)) * 8;
  const int t = perm[p];
  const float* src = x + (size_t)t * H_DIM + c;
  const float4 v0 = *(const float4*)(src);
  const float4 v1 = *(const float4*)(src + 4);
  short8 o;
  o[0] = (short)f2bf(v0.x); o[1] = (short)f2bf(v0.y);
  o[2] = (short)f2bf(v0.z); o[3] = (short)f2bf(v0.w);
  o[4] = (short)f2bf(v1.x); o[5] = (short)f2bf(v1.y);
  o[6] = (short)f2bf(v1.z); o[7] = (short)f2bf(v1.w);
  *(short8*)(xg + (size_t)p * H_DIM + c) = o;
}

// ---- grouped GEMM: ZERO LDS, ZERO barriers. Each wave owns a 64x32 output
// tile and streams A/B fragments straight from global into MFMA registers,
// 2-deep register prefetch. All waves fully independent -> max TLP.
template <int N_FULL, int K_FULL, int KLOOP, bool IS_FFN1>
__global__ __launch_bounds__(256) void moe_gemm(
    const unsigned short* __restrict__ A,   // [T_TOK][K_FULL] bf16 (perm order)
    const float* __restrict__ W,            // [E][K_FULL][N_FULL] f32
    const float* __restrict__ bias,         // [E][N_FULL] (FFN1 only)
    const int* __restrict__ tile_e, const int* __restrict__ tile_row,
    const int* __restrict__ tile_len, const int* __restrict__ ntiles,
    unsigned short* __restrict__ out_bf,    // FFN1 out
    float* __restrict__ part) {             // FFN2 partials [KSPLIT2][T_TOK][N_FULL]
  constexpr int KT = KLOOP / BK;   // 12 (even)

  const int slot = blockIdx.y;
  if (slot >= *ntiles) return;
  const int e    = tile_e[slot];
  const int row0 = tile_row[slot];
  const int len  = tile_len[slot];
  const int n0   = blockIdx.x * 64;
  const int kbase = blockIdx.z * KLOOP;
  const float* We = W + (size_t)e * K_FULL * N_FULL;

  const int lane = threadIdx.x & 63;
  const int wave = threadIdx.x >> 6;
  const int wr = wave >> 1, wc = wave & 1;   // 2x2 waves: 64 rows x 32 cols each
  const int lr  = lane & 15;
  const int lkb = (lane >> 4) << 3;          // 0,8,16,24

  // per-lane A row pointers (clamped; out-of-segment rows masked at store)
  const unsigned short* aptr[4];
#pragma unroll
  for (int m = 0; m < 4; ++m) {
    int row = row0 + wr * 64 + m * 16 + lr;
    row = row < T_TOK ? row : (T_TOK - 1);
    aptr[m] = A + (size_t)row * K_FULL + kbase + lkb;
  }
  // per-lane B base: col = n0 + wc*32 + lr, k-base = kbase + lkb
  const float* bp = We + (size_t)(kbase + lkb) * N_FULL + (n0 + wc * 32 + lr);

  f32x4 acc[4][2] = {};
  short8 a0[8], a1[8];     // [m][ks] A fragments, two K-steps in flight
  float  b0[32], b1[32];   // [ks][n][j] raw f32 B, two K-steps in flight

#define LOAD_A(kt, dst)                                                   \
  _Pragma("unroll") for (int m = 0; m < 4; ++m)                           \
  _Pragma("unroll") for (int ks = 0; ks < 2; ++ks)                        \
    dst[m * 2 + ks] = *(const short8*)(aptr[m] + (kt) * BK + ks * 32);
#define LOAD_B(kt, dst)                                                   \
  _Pragma("unroll") for (int ks = 0; ks < 2; ++ks)                        \
  _Pragma("unroll") for (int n = 0; n < 2; ++n)                           \
  _Pragma("unroll") for (int j = 0; j < 8; ++j)                           \
    dst[(ks * 2 + n) * 8 + j] =                                           \
        bp[(size_t)((kt) * BK + ks * 32 + j) * N_FULL + n * 16];
#define MFMA_STEP(asrc, bsrc)                                             \
  _Pragma("unroll") for (int ks = 0; ks < 2; ++ks) {                      \
    short8 bfr[2];                                                        \
    _Pragma("unroll") for (int n = 0; n < 2; ++n)                         \
    _Pragma("unroll") for (int j = 0; j < 8; ++j)                         \
      bfr[n][j] = (short)f2bf(bsrc[(ks * 2 + n) * 8 + j]);                \
    _Pragma("unroll") for (int m = 0; m < 4; ++m)                         \
    _Pragma("unroll") for (int n = 0; n < 2; ++n)                         \
      acc[m][n] = __builtin_amdgcn_mfma_f32_16x16x32_bf16(                \
          asrc[m * 2 + ks], bfr[n], acc[m][n], 0, 0, 0);                  \
  }

  LOAD_A(0, a0) LOAD_B(0, b0)
  LOAD_A(1, a1) LOAD_B(1, b1)
#pragma unroll 1
  for (int kt = 0; kt < KT - 2; kt += 2) {
    MFMA_STEP(a0, b0)
    LOAD_A(kt + 2, a0) LOAD_B(kt + 2, b0)
    MFMA_STEP(a1, b1)
    LOAD_A(kt + 3, a1) LOAD_B(kt + 3, b1)
  }
  MFMA_STEP(a0, b0)
  MFMA_STEP(a1, b1)
#undef LOAD_A
#undef LOAD_B
#undef MFMA_STEP

  // epilogue: C/D layout col=lane&15, row=(lane>>4)*4+j  [verified m89]
#pragma unroll
  for (int n = 0; n < 2; ++n) {
    const int gc = n0 + wc * 32 + n * 16 + lr;
    float bv = 0.f;
    if constexpr (IS_FFN1) bv = bias[(size_t)e * N_FULL + gc];
#pragma unroll
    for (int m = 0; m < 4; ++m) {
      const int rbase = wr * 64 + m * 16 + (lane >> 4) * 4;
#pragma unroll
      for (int j = 0; j < 4; ++j) {
        const int rl = rbase + j;
        if (rl < len) {
          if constexpr (IS_FFN1) {
            out_bf[(size_t)(row0 + rl) * N_FULL + gc] = f2bf(gelu_exact(acc[m][n][j] + bv));
          } else {
            part[((size_t)blockIdx.z * T_TOK + row0 + rl) * N_FULL + gc] = acc[m][n][j];
          }
        }
      }
    }
  }
}

// ---- kernel 5: split-K sum + bias2 + residual + LayerNorm ----
__global__ void ln_kernel(const float* __restrict__ part,
                          const float* __restrict__ x,
                          const int* __restrict__ perm,
                          const int* __restrict__ eidx,
                          const float* __restrict__ b2,
                          const float* __restrict__ gamma,
                          const float* __restrict__ beta,
                          float* __restrict__ out) {
  const int p = blockIdx.x;
  const int tid = threadIdx.x;  // 256
  const int t = perm[p];
  const int e = eidx[t];
  float v[3], s = 0.f, ss = 0.f;
#pragma unroll
  for (int i = 0; i < 3; ++i) {
    const int c = tid + i * 256;
    float a = x[(size_t)t * H_DIM + c] + b2[(size_t)e * H_DIM + c];
#pragma unroll
    for (int s4 = 0; s4 < KSPLIT2; ++s4)
      a += part[((size_t)s4 * T_TOK + p) * H_DIM + c];
    v[i] = a; s += a; ss += a * a;
  }
#pragma unroll
  for (int o = 32; o; o >>= 1) { s += __shfl_down(s, o); ss += __shfl_down(ss, o); }
  __shared__ float ps[4], pss[4];
  __shared__ float mu_s, ir_s;
  const int w = tid >> 6;
  if ((tid & 63) == 0) { ps[w] = s; pss[w] = ss; }
  __syncthreads();
  if (tid == 0) {
    const float S = ps[0] + ps[1] + ps[2] + ps[3];
    const float SS = pss[0] + pss[1] + pss[2] + pss[3];
    const float mu = S * (1.0f / H_DIM);
    const float var = SS * (1.0f / H_DIM) - mu * mu;
    mu_s = mu; ir_s = rsqrtf(var + 1e-12f);
  }
  __syncthreads();
  const float mu = mu_s, ir = ir_s;
#pragma unroll
  for (int i = 0; i < 3; ++i) {
    const int c = tid + i * 256;
    out[(size_t)t * H_DIM + c] = (v[i] - mu) * ir * gamma[c] + beta[c];
  }
}

extern "C" void kernel_launch(void* const* d_in, const int* in_sizes, int n_in,
                              void* d_out, int out_size, void* d_ws, size_t ws_size,
                              hipStream_t stream) {
  const float* x     = (const float*)d_in[0];
  const int*   eidx  = (const int*)d_in[1];
  const float* W1    = (const float*)d_in[2];
  const float* b1    = (const float*)d_in[3];
  const float* W2    = (const float*)d_in[4];
  const float* b2    = (const float*)d_in[5];
  const float* gamma = (const float*)d_in[6];
  const float* beta  = (const float*)d_in[7];
  float* out = (float*)d_out;

  char* ws = (char*)d_ws;
  int* perm     = (int*)(ws);
  int* tile_e   = (int*)(ws + 4096);
  int* tile_row = (int*)(ws + 4352);
  int* tile_len = (int*)(ws + 4608);
  int* ntiles   = (int*)(ws + 4864);
  unsigned short* xg    = (unsigned short*)(ws + 8192);          // 1.5 MB bf16
  unsigned short* inter = xg + (size_t)T_TOK * H_DIM;            // 6 MB bf16
  float* part = (float*)(ws + 8192 + 2 * (size_t)T_TOK * (H_DIM + I_DIM)); // 12 MB f32

  route_kernel<<<1, T_TOK, 0, stream>>>(eidx, perm, tile_e, tile_row, tile_len, ntiles);
  gather_kernel<<<(T_TOK * (H_DIM / 8) + 255) / 256, 256, 0, stream>>>(x, perm, xg);
  // FFN1: N=3072, K=768. grid 48 x 16 = 768 blocks
  moe_gemm<I_DIM, H_DIM, H_DIM, true><<<dim3(I_DIM / 64, MSLOTS, 1), 256, 0, stream>>>(
      xg, W1, b1, tile_e, tile_row, tile_len, ntiles, inter, nullptr);
  // FFN2: N=768, K=3072 split 4 x 768. grid 12 x 16 x 4 = 768 blocks
  moe_gemm<H_DIM, I_DIM, I_DIM / KSPLIT2, false><<<dim3(H_DIM / 64, MSLOTS, KSPLIT2), 256, 0, stream>>>(
      inter, W2, nullptr, tile_e, tile_row, tile_len, ntiles, nullptr, part);
  ln_kernel<<<T_TOK, 256, 0, stream>>>(part, x, perm, eidx, b2, gamma, beta, out);
  (void)in_sizes; (void)n_in; (void)out_size; (void)ws_size;
}

// Round 5
// 96.755 us; speedup vs baseline: 1.2281x; 1.2281x over previous
//
#include <hip/hip_runtime.h>
#include <math.h>

// ---- problem constants (fixed by reference) ----
#define T_TOK 1024
#define H_DIM 768
#define I_DIM 3072
#define E_NUM 8
#define BM    64
#define BK    64
#define MSLOTS 24   // max m-tiles: sum ceil(c_e/64) <= 1024/64 + 7 = 23
#define KSPLIT2 4   // FFN2 split-K factor

typedef __attribute__((ext_vector_type(8))) short  short8;   // 8 bf16 (4 VGPRs)
typedef __attribute__((ext_vector_type(4))) float  f32x4;
typedef __attribute__((ext_vector_type(4))) int    int4v;

__device__ __forceinline__ unsigned short f2bf(float f) {
  union { float f; unsigned u; } a; a.f = f;
  unsigned r = a.u + 0x7FFFu + ((a.u >> 16) & 1u);  // RTNE
  return (unsigned short)(r >> 16);
}
__device__ __forceinline__ float gelu_exact(float x) {
  return 0.5f * x * (1.0f + erff(x * 0.70710678118654752f));
}
// XOR swizzle: row-major [row][BK] bf16 tile -> conflict-free ds_read_b128 (G4).
__device__ __forceinline__ int swz(int row, int k) {
  return row * BK + (k ^ ((row & 7) << 3));
}

// ---- kernel 1: deterministic expert routing (ballot rank) + tile list ----
__global__ __launch_bounds__(1024) void route_kernel(
    const int* __restrict__ eidx, int* __restrict__ perm,
    int* __restrict__ tile_e, int* __restrict__ tile_row,
    int* __restrict__ tile_len, int* __restrict__ ntiles) {
  __shared__ int wcnt[16][E_NUM];   // per-wave per-expert count
  __shared__ int wpre[16][E_NUM];   // exclusive prefix over waves
  __shared__ int offsh[E_NUM + 1];
  const int t = threadIdx.x;        // 1024
  const int lane = t & 63, wave = t >> 6;
  const int e = eidx[t];
  unsigned long long myMask = 0;
#pragma unroll
  for (int ee = 0; ee < E_NUM; ++ee) {
    unsigned long long m = __ballot(e == ee);
    if (ee == e) myMask = m;
    if (lane == 0) wcnt[wave][ee] = __popcll(m);
  }
  const int rank = __popcll(myMask & ((1ull << lane) - 1ull));
  __syncthreads();
  if (t < 16 * E_NUM) {             // pair (w, e)
    const int w = t >> 3, ee = t & 7;
    int p = 0;
    for (int w2 = 0; w2 < w; ++w2) p += wcnt[w2][ee];
    wpre[w][ee] = p;
  }
  __syncthreads();
  if (t <= E_NUM) {
    int off = 0;
    for (int ee = 0; ee < t; ++ee) off += wpre[15][ee] + wcnt[15][ee];
    offsh[t] = off;
  }
  __syncthreads();
  perm[offsh[e] + wpre[wave][e] + rank] = t;
  if (t == 0) {
    int n = 0;
    for (int ee = 0; ee < E_NUM; ++ee)
      for (int r = offsh[ee]; r < offsh[ee + 1]; r += BM) {
        tile_e[n] = ee; tile_row[n] = r;
        tile_len[n] = min(offsh[ee + 1] - r, BM); ++n;
      }
    *ntiles = n;
    for (int i = n; i < MSLOTS; ++i) { tile_e[i] = 0; tile_row[i] = 0; tile_len[i] = 0; }
  }
}

// ---- kernel 2: gather x into perm order, f32 -> bf16 ----
__global__ void gather_kernel(const float* __restrict__ x,
                              const int* __restrict__ perm,
                              unsigned short* __restrict__ xg) {
  const int idx = blockIdx.x * 256 + threadIdx.x;
  if (idx >= T_TOK * (H_DIM / 8)) return;
  const int p = idx / (H_DIM / 8);
  const int c = (idx % (H_DIM / 8)) * 8;
  const int t = perm[p];
  const float* src = x + (size_t)t * H_DIM + c;
  const float4 v0 = *(const float4*)(src);
  const float4 v1 = *(const float4*)(src + 4);
  short8 o;
  o[0] = (short)f2bf(v0.x); o[1] = (short)f2bf(v0.y);
  o[2] = (short)f2bf(v0.z); o[3] = (short)f2bf(v0.w);
  o[4] = (short)f2bf(v1.x); o[5] = (short)f2bf(v1.y);
  o[6] = (short)f2bf(v1.z); o[7] = (short)f2bf(v1.w);
  *(short8*)(xg + (size_t)p * H_DIM + c) = o;
}

// ---- grouped GEMM, BM=64 x BN=64, 4 waves (2x2, 32x32 each), dbuf LDS,
// 2-deep register prefetch, 1 raw barrier per K-step. 32 KB LDS -> 5 blk/CU.
template <int N_FULL, int K_FULL, int KLOOP, bool IS_FFN1>
__global__ __launch_bounds__(256, 5) void moe_gemm(
    const unsigned short* __restrict__ A,   // [T_TOK][K_FULL] bf16 (perm order)
    const float* __restrict__ W,            // [E][K_FULL][N_FULL] f32
    const float* __restrict__ bias,         // [E][N_FULL] (FFN1 only)
    const int* __restrict__ tile_e, const int* __restrict__ tile_row,
    const int* __restrict__ tile_len, const int* __restrict__ ntiles,
    unsigned short* __restrict__ out_bf,    // FFN1 out
    float* __restrict__ part) {             // FFN2 partials [KSPLIT2][T_TOK][N_FULL]
  constexpr int BN = 64;
  constexpr int KT = KLOOP / BK;    // 12 / 12 (even)

  const int slot = blockIdx.y;
  if (slot >= *ntiles) return;
  const int e    = tile_e[slot];
  const int row0 = tile_row[slot];
  const int len  = tile_len[slot];
  const int n0   = blockIdx.x * BN;
  const int kbase = blockIdx.z * KLOOP;
  const float* We = W + (size_t)e * K_FULL * N_FULL;

  __shared__ unsigned short As[2][BM * BK];   // 2 x 8 KB
  __shared__ unsigned short Bs[2][BN * BK];   // 2 x 8 KB

  const int tid  = threadIdx.x;
  const int lane = tid & 63;
  const int wave = tid >> 6;
  const int wr = wave >> 1, wc = wave & 1;     // 2x2 waves: 32 rows x 32 cols each
  const int lr = lane & 15;
  const int lk = (lane >> 4) * 8;
  const int bn = tid & 63;                     // B stage: my column
  const int kb = tid >> 6;                     // B stage: my 16-k block

  f32x4 acc[2][2] = {};
  int4v areg0[2], areg1[2];
  float breg0[16], breg1[16];

  auto load_tile = [&](int kt, int4v* ar, float* br) {
    const int k0 = kbase + kt * BK;
#pragma unroll
    for (int i = 0; i < 2; ++i) {
      const int c = tid + i * 256;
      const int r = c >> 3, kc = (c & 7) << 3;
      int grow = row0 + r; grow = grow < T_TOK ? grow : (T_TOK - 1);
      ar[i] = *(const int4v*)(A + (size_t)grow * K_FULL + k0 + kc);
    }
    const float* wp = We + (size_t)(k0 + kb * 16) * N_FULL + n0 + bn;
#pragma unroll
    for (int j = 0; j < 16; ++j)
      br[j] = wp[(size_t)j * N_FULL];          // coalesced across lanes (n)
  };
  auto store_lds = [&](int buf, const int4v* ar, const float* br) {
#pragma unroll
    for (int i = 0; i < 2; ++i) {
      const int c = tid + i * 256;
      const int r = c >> 3, kc = (c & 7) << 3;
      *(int4v*)(&As[buf][swz(r, kc)]) = ar[i];
    }
    short8 p0, p1;
#pragma unroll
    for (int j = 0; j < 8; ++j) { p0[j] = (short)f2bf(br[j]); p1[j] = (short)f2bf(br[8 + j]); }
    *(short8*)(&Bs[buf][swz(bn, kb * 16)])     = p0;
    *(short8*)(&Bs[buf][swz(bn, kb * 16 + 8)]) = p1;
  };
  auto mfma_tile = [&](int buf) {
#pragma unroll
    for (int ks = 0; ks < 2; ++ks) {
      const int kk = ks * 32 + lk;
      short8 af[2], bfr[2];
#pragma unroll
      for (int m = 0; m < 2; ++m)
        af[m] = *(const short8*)(&As[buf][swz(wr * 32 + m * 16 + lr, kk)]);
#pragma unroll
      for (int n = 0; n < 2; ++n)
        bfr[n] = *(const short8*)(&Bs[buf][swz(wc * 32 + n * 16 + lr, kk)]);
#pragma unroll
      for (int m = 0; m < 2; ++m)
#pragma unroll
        for (int n = 0; n < 2; ++n)
          acc[m][n] = __builtin_amdgcn_mfma_f32_16x16x32_bf16(af[m], bfr[n], acc[m][n], 0, 0, 0);
    }
  };

  load_tile(0, areg0, breg0);
  load_tile(1, areg1, breg1);
#pragma unroll 1
  for (int kt = 0; kt < KT; kt += 2) {
    store_lds(0, areg0, breg0);
    if (kt + 2 < KT) load_tile(kt + 2, areg0, breg0);
    asm volatile("s_waitcnt lgkmcnt(0)" ::: "memory");
    __builtin_amdgcn_s_barrier();
    __builtin_amdgcn_sched_barrier(0);
    mfma_tile(0);
    store_lds(1, areg1, breg1);
    if (kt + 3 < KT) load_tile(kt + 3, areg1, breg1);
    asm volatile("s_waitcnt lgkmcnt(0)" ::: "memory");
    __builtin_amdgcn_s_barrier();
    __builtin_amdgcn_sched_barrier(0);
    mfma_tile(1);
  }

  // epilogue: C/D layout col=lane&15, row=(lane>>4)*4+j  [verified m89]
#pragma unroll
  for (int n = 0; n < 2; ++n) {
    const int gc = n0 + wc * 32 + n * 16 + lr;
    float bv = 0.f;
    if constexpr (IS_FFN1) bv = bias[(size_t)e * N_FULL + gc];
#pragma unroll
    for (int m = 0; m < 2; ++m) {
      const int rbase = wr * 32 + m * 16 + (lane >> 4) * 4;
#pragma unroll
      for (int j = 0; j < 4; ++j) {
        const int rl = rbase + j;
        if (rl < len) {
          if constexpr (IS_FFN1) {
            out_bf[(size_t)(row0 + rl) * N_FULL + gc] = f2bf(gelu_exact(acc[m][n][j] + bv));
          } else {
            part[((size_t)blockIdx.z * T_TOK + row0 + rl) * N_FULL + gc] = acc[m][n][j];
          }
        }
      }
    }
  }
}

// ---- kernel 5: split-K sum + bias2 + residual + LayerNorm ----
__global__ void ln_kernel(const float* __restrict__ part,
                          const float* __restrict__ x,
                          const int* __restrict__ perm,
                          const int* __restrict__ eidx,
                          const float* __restrict__ b2,
                          const float* __restrict__ gamma,
                          const float* __restrict__ beta,
                          float* __restrict__ out) {
  const int p = blockIdx.x;
  const int tid = threadIdx.x;  // 256
  const int t = perm[p];
  const int e = eidx[t];
  float v[3], s = 0.f, ss = 0.f;
#pragma unroll
  for (int i = 0; i < 3; ++i) {
    const int c = tid + i * 256;
    float a = x[(size_t)t * H_DIM + c] + b2[(size_t)e * H_DIM + c];
#pragma unroll
    for (int s4 = 0; s4 < KSPLIT2; ++s4)
      a += part[((size_t)s4 * T_TOK + p) * H_DIM + c];
    v[i] = a; s += a; ss += a * a;
  }
#pragma unroll
  for (int o = 32; o; o >>= 1) { s += __shfl_down(s, o); ss += __shfl_down(ss, o); }
  __shared__ float ps[4], pss[4];
  __shared__ float mu_s, ir_s;
  const int w = tid >> 6;
  if ((tid & 63) == 0) { ps[w] = s; pss[w] = ss; }
  __syncthreads();
  if (tid == 0) {
    const float S = ps[0] + ps[1] + ps[2] + ps[3];
    const float SS = pss[0] + pss[1] + pss[2] + pss[3];
    const float mu = S * (1.0f / H_DIM);
    const float var = SS * (1.0f / H_DIM) - mu * mu;
    mu_s = mu; ir_s = rsqrtf(var + 1e-12f);
  }
  __syncthreads();
  const float mu = mu_s, ir = ir_s;
#pragma unroll
  for (int i = 0; i < 3; ++i) {
    const int c = tid + i * 256;
    out[(size_t)t * H_DIM + c] = (v[i] - mu) * ir * gamma[c] + beta[c];
  }
}

extern "C" void kernel_launch(void* const* d_in, const int* in_sizes, int n_in,
                              void* d_out, int out_size, void* d_ws, size_t ws_size,
                              hipStream_t stream) {
  const float* x     = (const float*)d_in[0];
  const int*   eidx  = (const int*)d_in[1];
  const float* W1    = (const float*)d_in[2];
  const float* b1    = (const float*)d_in[3];
  const float* W2    = (const float*)d_in[4];
  const float* b2    = (const float*)d_in[5];
  const float* gamma = (const float*)d_in[6];
  const float* beta  = (const float*)d_in[7];
  float* out = (float*)d_out;

  char* ws = (char*)d_ws;
  int* perm     = (int*)(ws);
  int* tile_e   = (int*)(ws + 4096);
  int* tile_row = (int*)(ws + 4352);
  int* tile_len = (int*)(ws + 4608);
  int* ntiles   = (int*)(ws + 4864);
  unsigned short* xg    = (unsigned short*)(ws + 8192);          // 1.5 MB bf16
  unsigned short* inter = xg + (size_t)T_TOK * H_DIM;            // 6 MB bf16
  float* part = (float*)(ws + 8192 + 2 * (size_t)T_TOK * (H_DIM + I_DIM)); // 12 MB f32

  route_kernel<<<1, T_TOK, 0, stream>>>(eidx, perm, tile_e, tile_row, tile_len, ntiles);
  gather_kernel<<<(T_TOK * (H_DIM / 8) + 255) / 256, 256, 0, stream>>>(x, perm, xg);
  // FFN1: N=3072, K=768. grid 48 x 24 (real blocks ~48 x ~18)
  moe_gemm<I_DIM, H_DIM, H_DIM, true><<<dim3(I_DIM / 64, MSLOTS, 1), 256, 0, stream>>>(
      xg, W1, b1, tile_e, tile_row, tile_len, ntiles, inter, nullptr);
  // FFN2: N=768, K=3072 split 4 x 768. grid 12 x 24 x 4
  moe_gemm<H_DIM, I_DIM, I_DIM / KSPLIT2, false><<<dim3(H_DIM / 64, MSLOTS, KSPLIT2), 256, 0, stream>>>(
      inter, W2, nullptr, tile_e, tile_row, tile_len, ntiles, nullptr, part);
  ln_kernel<<<T_TOK, 256, 0, stream>>>(part, x, perm, eidx, b2, gamma, beta, out);
  (void)in_sizes; (void)n_in; (void)out_size; (void)ws_size;
}

// Round 6
// 73.649 us; speedup vs baseline: 1.6134x; 1.3137x over previous
//
#include <hip/hip_runtime.h>
#include <math.h>

// ---- problem constants (fixed by reference) ----
#define T_TOK 1024
#define H_DIM 768
#define I_DIM 3072
#define E_NUM 8
#define BM    128
#define BN    64
#define BK    64
#define MSLOTS 16    // max m-tiles at BM=128: 8 + 7 = 15
#define KSPLIT2 4    // FFN2 split-K factor
#define CONV_Y 8     // converter slots appended to FFN1 grid.y
#define NCONVB (48 * CONV_Y)                        // 384 converter blocks
#define CONV_CHUNKS (E_NUM * I_DIM * H_DIM / 8)     // 2359296 8-f32 chunks
#define CONV_PER_T (CONV_CHUNKS / (NCONVB * 512))   // 12

typedef __attribute__((ext_vector_type(8))) short  short8;   // 8 bf16
typedef __attribute__((ext_vector_type(4))) float  f32x4;

__device__ __forceinline__ unsigned short f2bf(float f) {
  union { float f; unsigned u; } a; a.f = f;
  unsigned r = a.u + 0x7FFFu + ((a.u >> 16) & 1u);  // RTNE
  return (unsigned short)(r >> 16);
}
__device__ __forceinline__ float gelu_exact(float x) {
  return 0.5f * x * (1.0f + erff(x * 0.70710678118654752f));
}
// XOR swizzle: row-major [row][BK] bf16 tile -> conflict-free ds_read_b128 (G4).
__device__ __forceinline__ int swz(int row, int k) {
  return row * BK + (k ^ ((row & 7) << 3));
}
// async global->LDS, 16B per lane. LDS dest = wave-uniform base + lane*16.
__device__ __forceinline__ void gll16(const void* g, void* l) {
  __builtin_amdgcn_global_load_lds(
      (const __attribute__((address_space(1))) void*)g,
      (__attribute__((address_space(3))) void*)l, 16, 0, 0);
}

// ---- kernel 1: deterministic expert routing (ballot rank) + tile list ----
__global__ __launch_bounds__(1024) void route_kernel(
    const int* __restrict__ eidx, int* __restrict__ perm,
    int* __restrict__ tile_e, int* __restrict__ tile_row,
    int* __restrict__ tile_len, int* __restrict__ ntiles) {
  __shared__ int wcnt[16][E_NUM];
  __shared__ int wpre[16][E_NUM];
  __shared__ int offsh[E_NUM + 1];
  const int t = threadIdx.x;        // 1024
  const int lane = t & 63, wave = t >> 6;
  const int e = eidx[t];
  unsigned long long myMask = 0;
#pragma unroll
  for (int ee = 0; ee < E_NUM; ++ee) {
    unsigned long long m = __ballot(e == ee);
    if (ee == e) myMask = m;
    if (lane == 0) wcnt[wave][ee] = __popcll(m);
  }
  const int rank = __popcll(myMask & ((1ull << lane) - 1ull));
  __syncthreads();
  if (t < 16 * E_NUM) {
    const int w = t >> 3, ee = t & 7;
    int p = 0;
    for (int w2 = 0; w2 < w; ++w2) p += wcnt[w2][ee];
    wpre[w][ee] = p;
  }
  __syncthreads();
  if (t <= E_NUM) {
    int off = 0;
    for (int ee = 0; ee < t; ++ee) off += wpre[15][ee] + wcnt[15][ee];
    offsh[t] = off;
  }
  __syncthreads();
  perm[offsh[e] + wpre[wave][e] + rank] = t;
  if (t == 0) {
    int n = 0;
    for (int ee = 0; ee < E_NUM; ++ee)
      for (int r = offsh[ee]; r < offsh[ee + 1]; r += BM) {
        tile_e[n] = ee; tile_row[n] = r;
        tile_len[n] = min(offsh[ee + 1] - r, BM); ++n;
      }
    *ntiles = n;
    for (int i = n; i < MSLOTS; ++i) { tile_e[i] = 0; tile_row[i] = 0; tile_len[i] = 0; }
  }
}

// ---- kernel 2: gather x into perm order, f32 -> bf16 ----
__global__ void gather_kernel(const float* __restrict__ x,
                              const int* __restrict__ perm,
                              unsigned short* __restrict__ xg) {
  const int idx = blockIdx.x * 256 + threadIdx.x;
  if (idx >= T_TOK * (H_DIM / 8)) return;
  const int p = idx / (H_DIM / 8);
  const int c = (idx % (H_DIM / 8)) * 8;
  const int t = perm[p];
  const float* src = x + (size_t)t * H_DIM + c;
  const float4 v0 = *(const float4*)(src);
  const float4 v1 = *(const float4*)(src + 4);
  short8 o;
  o[0] = (short)f2bf(v0.x); o[1] = (short)f2bf(v0.y);
  o[2] = (short)f2bf(v0.z); o[3] = (short)f2bf(v0.w);
  o[4] = (short)f2bf(v1.x); o[5] = (short)f2bf(v1.y);
  o[6] = (short)f2bf(v1.z); o[7] = (short)f2bf(v1.w);
  *(short8*)(xg + (size_t)p * H_DIM + c) = o;
}

// ---- grouped GEMM, BM=128 x BN=64, 8 waves (4x2, 32x32 each), dbuf LDS ----
// A staged via global_load_lds (pre-swizzled source, linear LDS dest).
// B reg-staged (f32->bf16 cvt for FFN1 / raw bf16 for FFN2-converted).
// FFN1 grid.y slots >= MSLOTS run the overlapped W2 f32->bf16 converter.
template <int N_FULL, int K_FULL, int KLOOP, bool IS_FFN1, bool B_BF16>
__global__ __launch_bounds__(512, 4) void moe_gemm(
    const unsigned short* __restrict__ A,   // [T_TOK][K_FULL] bf16 (perm order)
    const void* __restrict__ Wv,            // [E][K_FULL][N_FULL] f32 or bf16
    const float* __restrict__ bias,         // [E][N_FULL] (FFN1 only)
    const int* __restrict__ tile_e, const int* __restrict__ tile_row,
    const int* __restrict__ tile_len, const int* __restrict__ ntiles,
    unsigned short* __restrict__ out_bf,    // FFN1 out
    float* __restrict__ part,               // FFN2 partials [KSPLIT2][T_TOK][N_FULL]
    const float* __restrict__ convSrc,      // W2 f32 (FFN1 only)
    unsigned short* __restrict__ convDst) { // w2bf
  constexpr int KT = KLOOP / BK;            // 12 (even)
  const int tid  = threadIdx.x;
  const int slot = blockIdx.y;

  if constexpr (IS_FFN1) {
    if (slot >= MSLOTS) {                   // overlapped W2 f32->bf16 stream
      const int cb  = blockIdx.x + 48 * (slot - MSLOTS);
      const int lin = cb * 512 + tid;
      const float4* s4 = (const float4*)convSrc;
      short8* d8 = (short8*)convDst;
#pragma unroll
      for (int j = 0; j < CONV_PER_T; ++j) {
        const int idx = j * (NCONVB * 512) + lin;
        const float4 a = s4[2 * idx], b = s4[2 * idx + 1];
        short8 o;
        o[0] = (short)f2bf(a.x); o[1] = (short)f2bf(a.y);
        o[2] = (short)f2bf(a.z); o[3] = (short)f2bf(a.w);
        o[4] = (short)f2bf(b.x); o[5] = (short)f2bf(b.y);
        o[6] = (short)f2bf(b.z); o[7] = (short)f2bf(b.w);
        d8[idx] = o;
      }
      return;
    }
  }
  if (slot >= *ntiles) return;
  const int e    = tile_e[slot];
  const int row0 = tile_row[slot];
  const int len  = tile_len[slot];
  const int n0   = blockIdx.x * BN;
  const int kbase = blockIdx.z * KLOOP;

  __shared__ unsigned short As[2][BM * BK];   // 2 x 16 KB, linear chunk order
  __shared__ unsigned short Bs[2][BN * BK];   // 2 x  8 KB, [n][k] swizzled

  const int lane = tid & 63;
  const int wave = tid >> 6;
  const int wm = wave >> 1, wn = wave & 1;    // 4x2 waves: 32 rows x 32 cols each
  const int lr = lane & 15;
  const int lk = (lane >> 4) * 8;

  // A gll addressing: linear LDS chunk c holds global (r, kc ^ xor(r)) so the
  // swizzled ds_read below sees the standard layout (pre-swizzled source, m173).
  const unsigned short* agsrc[2];
  int aoff[2];
#pragma unroll
  for (int i = 0; i < 2; ++i) {
    const int c = tid + i * 512;
    const int r = c >> 3, kc = (c & 7) << 3;
    int grow = row0 + r; grow = grow < T_TOK ? grow : (T_TOK - 1);
    agsrc[i] = A + (size_t)grow * K_FULL + kbase + (kc ^ ((r & 7) << 3));
    aoff[i]  = ((tid & ~63) + i * 512) * 8;   // wave-uniform 16B-chunk base
  }
  // B staging: thread owns (col n, 8 consecutive k) -> coalesced row reads
  const int bn_ = tid & 63, kb8 = (tid >> 6) * 8;
  const float* wpf = nullptr; const unsigned short* wph = nullptr;
  if constexpr (B_BF16)
    wph = (const unsigned short*)Wv + (size_t)e * K_FULL * N_FULL +
          (size_t)(kbase + kb8) * N_FULL + n0 + bn_;
  else
    wpf = (const float*)Wv + (size_t)e * K_FULL * N_FULL +
          (size_t)(kbase + kb8) * N_FULL + n0 + bn_;

  f32x4 acc[2][2] = {};
  float bregA[8], bregB[8];
  unsigned short uregA[8], uregB[8];

  auto issueA = [&](int kt, int buf) {
#pragma unroll
    for (int i = 0; i < 2; ++i)
      gll16(agsrc[i] + kt * BK, &As[buf][aoff[i]]);
  };
  auto loadB = [&](int kt, float* bf, unsigned short* bh) {
#pragma unroll
    for (int j = 0; j < 8; ++j) {
      if constexpr (B_BF16) bh[j] = wph[(size_t)(kt * BK + j) * N_FULL];
      else                  bf[j] = wpf[(size_t)(kt * BK + j) * N_FULL];
    }
  };
  auto writeB = [&](int buf, const float* bf, const unsigned short* bh) {
    short8 p;
#pragma unroll
    for (int j = 0; j < 8; ++j)
      p[j] = B_BF16 ? (short)bh[j] : (short)f2bf(bf[j]);
    *(short8*)(&Bs[buf][swz(bn_, kb8)]) = p;
  };
  auto mfma_tile = [&](int buf) {
#pragma unroll
    for (int ks = 0; ks < 2; ++ks) {
      const int kk = ks * 32 + lk;
      short8 af[2], bfr[2];
#pragma unroll
      for (int m = 0; m < 2; ++m)
        af[m] = *(const short8*)(&As[buf][swz(wm * 32 + m * 16 + lr, kk)]);
#pragma unroll
      for (int n = 0; n < 2; ++n)
        bfr[n] = *(const short8*)(&Bs[buf][swz(wn * 32 + n * 16 + lr, kk)]);
#pragma unroll
      for (int m = 0; m < 2; ++m)
#pragma unroll
        for (int n = 0; n < 2; ++n)
          acc[m][n] = __builtin_amdgcn_mfma_f32_16x16x32_bf16(af[m], bfr[n], acc[m][n], 0, 0, 0);
    }
  };

  issueA(0, 0); loadB(0, bregA, uregA);
#pragma unroll 1
  for (int kt = 0; kt < KT; kt += 2) {
    // P1 (tile kt, buf0): everything issued earlier has landed after this
    asm volatile("s_waitcnt vmcnt(0)" ::: "memory");
    writeB(0, bregA, uregA);
    asm volatile("s_waitcnt lgkmcnt(0)" ::: "memory");
    __builtin_amdgcn_s_barrier();   // all waves: buf0 ready; prior buf1 reads done
    __builtin_amdgcn_sched_barrier(0);
    issueA(kt + 1, 1); loadB(kt + 1, bregB, uregB);   // lands during mfma
    mfma_tile(0);
    // P2 (tile kt+1, buf1)
    asm volatile("s_waitcnt vmcnt(0)" ::: "memory");
    writeB(1, bregB, uregB);
    asm volatile("s_waitcnt lgkmcnt(0)" ::: "memory");
    __builtin_amdgcn_s_barrier();
    __builtin_amdgcn_sched_barrier(0);
    if (kt + 2 < KT) { issueA(kt + 2, 0); loadB(kt + 2, bregA, uregA); }
    mfma_tile(1);
  }

  // epilogue: C/D layout col=lane&15, row=(lane>>4)*4+j  [verified m89]
#pragma unroll
  for (int n = 0; n < 2; ++n) {
    const int gc = n0 + wn * 32 + n * 16 + lr;
    float bv = 0.f;
    if constexpr (IS_FFN1) bv = bias[(size_t)e * N_FULL + gc];
#pragma unroll
    for (int m = 0; m < 2; ++m) {
      const int rbase = wm * 32 + m * 16 + (lane >> 4) * 4;
#pragma unroll
      for (int j = 0; j < 4; ++j) {
        const int rl = rbase + j;
        if (rl < len) {
          if constexpr (IS_FFN1) {
            out_bf[(size_t)(row0 + rl) * N_FULL + gc] = f2bf(gelu_exact(acc[m][n][j] + bv));
          } else {
            part[((size_t)blockIdx.z * T_TOK + row0 + rl) * N_FULL + gc] = acc[m][n][j];
          }
        }
      }
    }
  }
}

// ---- kernel 5: split-K sum + bias2 + residual + LayerNorm ----
__global__ void ln_kernel(const float* __restrict__ part,
                          const float* __restrict__ x,
                          const int* __restrict__ perm,
                          const int* __restrict__ eidx,
                          const float* __restrict__ b2,
                          const float* __restrict__ gamma,
                          const float* __restrict__ beta,
                          float* __restrict__ out) {
  const int p = blockIdx.x;
  const int tid = threadIdx.x;  // 256
  const int t = perm[p];
  const int e = eidx[t];
  float v[3], s = 0.f, ss = 0.f;
#pragma unroll
  for (int i = 0; i < 3; ++i) {
    const int c = tid + i * 256;
    float a = x[(size_t)t * H_DIM + c] + b2[(size_t)e * H_DIM + c];
#pragma unroll
    for (int s4 = 0; s4 < KSPLIT2; ++s4)
      a += part[((size_t)s4 * T_TOK + p) * H_DIM + c];
    v[i] = a; s += a; ss += a * a;
  }
#pragma unroll
  for (int o = 32; o; o >>= 1) { s += __shfl_down(s, o); ss += __shfl_down(ss, o); }
  __shared__ float ps[4], pss[4];
  __shared__ float mu_s, ir_s;
  const int w = tid >> 6;
  if ((tid & 63) == 0) { ps[w] = s; pss[w] = ss; }
  __syncthreads();
  if (tid == 0) {
    const float S = ps[0] + ps[1] + ps[2] + ps[3];
    const float SS = pss[0] + pss[1] + pss[2] + pss[3];
    const float mu = S * (1.0f / H_DIM);
    const float var = SS * (1.0f / H_DIM) - mu * mu;
    mu_s = mu; ir_s = rsqrtf(var + 1e-12f);
  }
  __syncthreads();
  const float mu = mu_s, ir = ir_s;
#pragma unroll
  for (int i = 0; i < 3; ++i) {
    const int c = tid + i * 256;
    out[(size_t)t * H_DIM + c] = (v[i] - mu) * ir * gamma[c] + beta[c];
  }
}

extern "C" void kernel_launch(void* const* d_in, const int* in_sizes, int n_in,
                              void* d_out, int out_size, void* d_ws, size_t ws_size,
                              hipStream_t stream) {
  const float* x     = (const float*)d_in[0];
  const int*   eidx  = (const int*)d_in[1];
  const float* W1    = (const float*)d_in[2];
  const float* b1    = (const float*)d_in[3];
  const float* W2    = (const float*)d_in[4];
  const float* b2    = (const float*)d_in[5];
  const float* gamma = (const float*)d_in[6];
  const float* beta  = (const float*)d_in[7];
  float* out = (float*)d_out;

  char* ws = (char*)d_ws;
  int* perm     = (int*)(ws);
  int* tile_e   = (int*)(ws + 4096);
  int* tile_row = (int*)(ws + 4352);
  int* tile_len = (int*)(ws + 4608);
  int* ntiles   = (int*)(ws + 4864);
  size_t off = 8192;
  unsigned short* xg = (unsigned short*)(ws + off);  off += (size_t)2 * T_TOK * H_DIM;  // 1.5 MB
  unsigned short* inter = (unsigned short*)(ws + off); off += (size_t)2 * T_TOK * I_DIM; // 6 MB
  float* part = (float*)(ws + off); off += (size_t)4 * KSPLIT2 * T_TOK * H_DIM;          // 12 MB
  unsigned short* w2bf = (unsigned short*)(ws + off);
  const size_t need = off + (size_t)2 * E_NUM * I_DIM * H_DIM;                           // ~58.2 MB
  const bool useBF = ws_size >= need;

  route_kernel<<<1, T_TOK, 0, stream>>>(eidx, perm, tile_e, tile_row, tile_len, ntiles);
  gather_kernel<<<(T_TOK * (H_DIM / 8) + 255) / 256, 256, 0, stream>>>(x, perm, xg);
  if (useBF) {
    // FFN1 + overlapped W2->bf16 conversion
    moe_gemm<I_DIM, H_DIM, H_DIM, true, false>
        <<<dim3(I_DIM / BN, MSLOTS + CONV_Y, 1), 512, 0, stream>>>(
        xg, W1, b1, tile_e, tile_row, tile_len, ntiles, inter, nullptr, W2, w2bf);
    moe_gemm<H_DIM, I_DIM, I_DIM / KSPLIT2, false, true>
        <<<dim3(H_DIM / BN, MSLOTS, KSPLIT2), 512, 0, stream>>>(
        inter, w2bf, nullptr, tile_e, tile_row, tile_len, ntiles, nullptr, part,
        nullptr, nullptr);
  } else {
    moe_gemm<I_DIM, H_DIM, H_DIM, true, false>
        <<<dim3(I_DIM / BN, MSLOTS, 1), 512, 0, stream>>>(
        xg, W1, b1, tile_e, tile_row, tile_len, ntiles, inter, nullptr, nullptr, nullptr);
    moe_gemm<H_DIM, I_DIM, I_DIM / KSPLIT2, false, false>
        <<<dim3(H_DIM / BN, MSLOTS, KSPLIT2), 512, 0, stream>>>(
        inter, W2, nullptr, tile_e, tile_row, tile_len, ntiles, nullptr, part,
        nullptr, nullptr);
  }
  ln_kernel<<<T_TOK, 256, 0, stream>>>(part, x, perm, eidx, b2, gamma, beta, out);
  (void)in_sizes; (void)n_in; (void)out_size;
}